// Round 9
// baseline (221.641 us; speedup 1.0000x reference)
//
#include <hip/hip_runtime.h>

// Problem: B=2, H=32, S=8192, D=128, T=512, fp32.
// out = (updated_k, updated_v) concatenated flat: each B*H*S*D = 67,108,864 floats.
//
// Strategy: delegate the bulk copy (94% of traffic) to the driver's tuned
// D2D blit via hipMemcpyAsync (graph-capture legal per harness), then run a
// tiny forward-scatter kernel for the 512 new rows per (b,h). Stream order
// serializes copy -> scatter, giving the overwrite semantics.

#define S_LEN 8192
#define T_LEN 512
#define D_DIM 128
#define BH    64            // B*H
#define ELEMS_PER_TENSOR (BH * S_LEN * D_DIM)      // 67,108,864 floats
#define BYTES_PER_TENSOR ((size_t)ELEMS_PER_TENSOR * 4)  // 256 MiB
#define VECS_PER_BH      (S_LEN * (D_DIM / 4))     // 262,144 float4s per bh slice
#define NEW_VECS_PER_BH  (T_LEN * (D_DIM / 4))     // 16,384 float4s per bh slice

// Native clang vector type.
typedef float f4_t __attribute__((ext_vector_type(4)));

// --- forward scatter of the new rows ------------------------------------
// grid (4096, 2), block 256: one float4 per thread per tensor.
// positions may arrive as int32 or int64; detect by range-checking the first
// two 8-byte reads (int32 read as int64 misparses element 1). L2-hot.
__global__ __launch_bounds__(256) void ssc_scatter(
    const f4_t* __restrict__ nk, const f4_t* __restrict__ nv,
    const void* __restrict__ pos,
    f4_t* __restrict__ ok, f4_t* __restrict__ ov) {
    const int v   = blockIdx.x * 256 + threadIdx.x;   // 0 .. 1,048,575
    const int d4  = v & 31;
    const int t   = (v >> 5) & (T_LEN - 1);
    const int bh  = v >> 14;

    const long long* p64 = (const long long*)pos;
    const int*       p32 = (const int*)pos;
    long long a = p64[0], b = p64[1];
    bool is64 = (a >= 0) && (a < S_LEN) && (b >= 0) && (b < S_LEN) && (a != b);
    int s = is64 ? (int)p64[t] : p32[t];
    if ((unsigned)s >= (unsigned)S_LEN) return;       // defensive

    const f4_t* __restrict__ src = blockIdx.y ? nv : nk;
    f4_t*       __restrict__ dst = blockIdx.y ? ov : ok;
    dst[bh * VECS_PER_BH + s * 32 + d4] = src[v];
}

extern "C" void kernel_launch(void* const* d_in, const int* in_sizes, int n_in,
                              void* d_out, int out_size, void* d_ws, size_t ws_size,
                              hipStream_t stream) {
    const void* ck = d_in[0];
    const void* cv = d_in[1];
    const f4_t* nk = (const f4_t*)d_in[2];
    const f4_t* nv = (const f4_t*)d_in[3];
    const void* pos = d_in[4];

    float* out = (float*)d_out;
    f4_t* ok = (f4_t*)out;
    f4_t* ov = (f4_t*)(out + ELEMS_PER_TENSOR);

    // Bulk copy: driver-tuned D2D blit.
    hipMemcpyAsync(ok, ck, BYTES_PER_TENSOR, hipMemcpyDeviceToDevice, stream);
    hipMemcpyAsync(ov, cv, BYTES_PER_TENSOR, hipMemcpyDeviceToDevice, stream);

    // Overwrite the 512 updated rows per (b,h).
    ssc_scatter<<<dim3(4096, 2), 256, 0, stream>>>(nk, nv, pos, ok, ov);
}

// Round 10
// 194.854 us; speedup vs baseline: 1.1375x; 1.1375x over previous
//
#include <hip/hip_runtime.h>

// Problem: B=2, H=32, S=8192, D=128, T=512, fp32.
// out = (updated_k, updated_v) concatenated flat: each B*H*S*D = 67,108,864 floats.
//
// FINAL (R4 structure, best measured: 199.7 us = 5.38 TB/s combined traffic).
// Fused copy+scatter, minimal traffic (1.074 GB): un-replaced cache rows are
// read once, replaced rows sourced from new_k/new_v, everything written once.
// Beats hipMemcpyAsync D2D blit + scatter (221.6 us) and all structural
// variants tried (plain stores 214, deep batch 244, split memcpy 250,
// contiguous chunks 209, K/V interleaved 235).

#define S_LEN 8192
#define T_LEN 512
#define D_DIM 128
#define BH    64            // B*H
#define ELEMS_PER_TENSOR (BH * S_LEN * D_DIM)      // 67,108,864 floats
#define VECS_PER_BH      (S_LEN * (D_DIM / 4))     // 262,144 float4s per bh slice
#define NEW_VECS_PER_BH  (T_LEN * (D_DIM / 4))     // 16,384 float4s per bh slice

// Native clang vector type — __builtin_nontemporal_* requires this.
typedef float f4_t __attribute__((ext_vector_type(4)));

// --- single fused kernel -------------------------------------------------
// grid = (1024, 2, 2), block = 256.
//   blockIdx.x: (s,d4) chunk — block covers 8 consecutive seq rows.
//   blockIdx.y: which half of the 64 bh slices.
//   blockIdx.z: 0 = K tensor, 1 = V tensor (1 read + 1 write stream/thread).
// Inverse position map built PER BLOCK in LDS (8 entries; 256 threads scan
// the 512 positions, L2-hot). t and the new-vs-cache branch are hoisted out
// of the bh loop (uniform per thread). Inner loop: compiler-interleaved
// unroll-4 of nontemporal dwordx4 load+store pairs.
__global__ __launch_bounds__(256) void ssc_fused(
    const f4_t* __restrict__ ck, const f4_t* __restrict__ cv,
    const f4_t* __restrict__ nk, const f4_t* __restrict__ nv,
    const void* __restrict__ pos,
    f4_t* __restrict__ ok, f4_t* __restrict__ ov) {

    __shared__ int lmap[8];
    const int ltid = threadIdx.x;
    const int s0   = blockIdx.x * 8;           // first seq row of this block

    if (ltid < 8) lmap[ltid] = -1;
    __syncthreads();

    // positions may arrive as int32 or int64; detect by range-checking the
    // first two 8-byte reads (int32 read as int64 misparses element 1).
    {
        const long long* p64 = (const long long*)pos;
        const int*       p32 = (const int*)pos;
        long long a = p64[0], b = p64[1];
        bool is64 = (a >= 0) && (a < S_LEN) && (b >= 0) && (b < S_LEN) && (a != b);
        #pragma unroll
        for (int j = ltid; j < T_LEN; j += 256) {
            int p = is64 ? (int)p64[j] : p32[j];
            unsigned r = (unsigned)(p - s0);
            if (r < 8u) lmap[r] = j;
        }
    }
    __syncthreads();

    const int tid = blockIdx.x * 256 + ltid;   // 0 .. 262143
    const int d4  = tid & 31;                  // 32 float4s per row
    const int s   = tid >> 5;                  // 0 .. 8191
    const int t   = lmap[s & 7];

    // pick tensor (grid-uniform)
    const f4_t* csrc = blockIdx.z ? cv : ck;
    const f4_t* nsrc = blockIdx.z ? nv : nk;
    f4_t*       odst = blockIdx.z ? ov : ok;

    const int bh0    = blockIdx.y * (BH / 2);
    const int dstOff = s * 32 + d4;            // vec index within a bh slice

    const f4_t* src;
    int sstride;
    if (t >= 0) { src = nsrc + (t * 32 + d4) + bh0 * NEW_VECS_PER_BH; sstride = NEW_VECS_PER_BH; }
    else        { src = csrc + dstOff          + bh0 * VECS_PER_BH;    sstride = VECS_PER_BH; }
    f4_t* dst = odst + dstOff + bh0 * VECS_PER_BH;

    #pragma unroll 4
    for (int i = 0; i < BH / 2; ++i) {
        f4_t v = __builtin_nontemporal_load(src);
        __builtin_nontemporal_store(v, dst);
        src += sstride;
        dst += VECS_PER_BH;
    }
}

extern "C" void kernel_launch(void* const* d_in, const int* in_sizes, int n_in,
                              void* d_out, int out_size, void* d_ws, size_t ws_size,
                              hipStream_t stream) {
    const f4_t* ck = (const f4_t*)d_in[0];
    const f4_t* cv = (const f4_t*)d_in[1];
    const f4_t* nk = (const f4_t*)d_in[2];
    const f4_t* nv = (const f4_t*)d_in[3];
    const void* pos = d_in[4];

    float* out = (float*)d_out;
    f4_t* ok = (f4_t*)out;
    f4_t* ov = (f4_t*)(out + ELEMS_PER_TENSOR);

    ssc_fused<<<dim3(1024, 2, 2), 256, 0, stream>>>(ck, cv, nk, nv, pos, ok, ov);
}